// Round 2
// baseline (196.901 us; speedup 1.0000x reference)
//
#include <hip/hip_runtime.h>

#define NN 64
#define NITER 12
#define MSTRIDE 68   // floats: 272 B row pitch — 16B-aligned, bank-uniform for b128

// One block (64 threads = 1 wave) per (s,t) matrix. Coalesced global load,
// transpose to row-per-lane registers via a 32-row LDS stage (two halves),
// then power-iterate v <- M v (column-stochastic => sum(v) invariant).
__global__ __launch_bounds__(64, 4) void perron_kernel(
    const float* __restrict__ x,
    const float* __restrict__ wt,
    const float* __restrict__ rconst,
    float* __restrict__ ws)
{
    const int st = blockIdx.x;        // 0..4095  (st = s*64 + t)
    const int m  = threadIdx.x;       // 0..63
    const int s  = st >> 6;

    const float4* M4 = (const float4*)(rconst + (size_t)st * (NN * NN));

    __shared__ float mstage[32 * MSTRIDE];   // 8704 B staging (half matrix)
    __shared__ float vbuf[2][NN];            // 512 B double-buffered vector

    // Register file for my row (row m of M): 16 x float4 = 64 VGPRs.
    float4 row[16];

    const int h  = m >> 4;    // sub-row within a coalesced instr (0..3)
    const int c4 = m & 15;    // col/4 within a coalesced instr (0..15)

    #pragma unroll
    for (int half = 0; half < 2; ++half) {
        // Stage 32 rows = 8 coalesced float4 loads (1 KB/instr), in two
        // chunks of 4 to keep transient VGPRs low.
        #pragma unroll
        for (int chunk = 0; chunk < 2; ++chunk) {
            float4 tmp[4];
            #pragma unroll
            for (int j = 0; j < 4; ++j) {
                const int q = half * 8 + chunk * 4 + j;     // instr index
                tmp[j] = M4[q * 64 + m];                    // contiguous 1 KB
            }
            if (chunk == 0) __syncthreads();   // protect mstage reuse across halves
            #pragma unroll
            for (int j = 0; j < 4; ++j) {
                const int q  = half * 8 + chunk * 4 + j;
                const int rb = 4 * (q - half * 8) + h;      // row within stage (0..31)
                *(float4*)(mstage + rb * MSTRIDE + 4 * c4) = tmp[j];
            }
        }
        __syncthreads();
        // Lanes whose row lives in this half pull it: 16 x ds_read_b128,
        // start banks spread uniformly (stride 272 B).
        if ((m >> 5) == half) {
            const float4* src = (const float4*)(mstage + (m & 31) * MSTRIDE);
            #pragma unroll
            for (int q = 0; q < 16; ++q) row[q] = src[q];
        }
    }

    vbuf[0][m] = 1.0f / NN;
    __syncthreads();

    int cur = 0;
    #pragma unroll 1
    for (int it = 0; it < NITER; ++it) {
        const float4* v4 = (const float4*)vbuf[cur];
        float acc = 0.0f;
        #pragma unroll
        for (int q = 0; q < 16; ++q) {
            float4 v = v4[q];               // same-address broadcast reads
            acc += row[q].x * v.x;
            acc += row[q].y * v.y;
            acc += row[q].z * v.z;
            acc += row[q].w * v.w;
        }
        cur ^= 1;
        vbuf[cur][m] = acc;                 // sum(v) preserved, no renorm
        __syncthreads();
    }

    // coef = x[s,t] * wt[s,t] * M[s][s] / v[s]  (all uniform scalar loads)
    const float Mss  = rconst[(size_t)st * (NN * NN) + s * NN + s];
    const float coef = x[st] * wt[st] * Mss / vbuf[cur][s];
    ws[(size_t)st * NN + m] = coef * vbuf[cur][m];     // coalesced 256 B store
}

// Stage 1: 16 blocks; block b reduces sts [256b, 256b+256) fully coalesced.
__global__ __launch_bounds__(256) void reduce1_kernel(
    const float* __restrict__ ws, float* __restrict__ part)
{
    const int b = blockIdx.x;
    const int t = threadIdx.x;
    const int n = t & 63;       // output index
    const int g = t >> 6;       // wave id = st subgroup
    float acc = 0.0f;
    #pragma unroll
    for (int k = 0; k < 64; ++k) {
        const int st = (b << 8) + (k << 2) + g;
        acc += ws[(size_t)st * NN + n];     // 256 B contiguous per wave
    }
    __shared__ float p[4][NN];
    p[g][n] = acc;
    __syncthreads();
    if (t < NN) part[b * NN + t] = p[0][t] + p[1][t] + p[2][t] + p[3][t];
}

// Stage 2: finisher.
__global__ __launch_bounds__(64) void reduce2_kernel(
    const float* __restrict__ part, float* __restrict__ out)
{
    const int n = threadIdx.x;
    float acc = 0.0f;
    #pragma unroll
    for (int b = 0; b < 16; ++b) acc += part[b * NN + n];
    out[n] = acc;
}

extern "C" void kernel_launch(void* const* d_in, const int* in_sizes, int n_in,
                              void* d_out, int out_size, void* d_ws, size_t ws_size,
                              hipStream_t stream) {
    const float* x      = (const float*)d_in[0];   // (64,64)
    const float* wt     = (const float*)d_in[1];   // (64,64)
    // d_in[2]=weights_r, d_in[3]=r_zeros unused: weights_r * 0 == 0
    const float* rconst = (const float*)d_in[4];   // (64,64,64,64)
    float* out  = (float*)d_out;                   // (64,)
    float* ws   = (float*)d_ws;                    // 4096*64 floats = 1 MB
    float* part = ws + 4096 * NN;                  // 16*64 floats

    perron_kernel<<<dim3(NN * NN), dim3(NN), 0, stream>>>(x, wt, rconst, ws);
    reduce1_kernel<<<dim3(16), dim3(256), 0, stream>>>(ws, part);
    reduce2_kernel<<<dim3(1), dim3(NN), 0, stream>>>(part, out);
}

// Round 3
// 184.735 us; speedup vs baseline: 1.0659x; 1.0659x over previous
//
#include <hip/hip_runtime.h>

#define NN 64
#define NITER 10

// One block (1 wave, 64 threads) per (s,t) matrix.
// Phase 1: coalesced global load (16 x 1KB) -> XOR-swizzled LDS store.
// Phase 2: lane m pulls row m into 16 float4 REGISTERS (conflict-free reads).
// Phase 3: 10 power iterations v <- M v entirely from registers + a tiny
//          LDS vector (broadcast reads). Column-stochastic => sum(v) fixed.
__global__ __launch_bounds__(64) void perron_kernel(
    const float* __restrict__ x,
    const float* __restrict__ wt,
    const float* __restrict__ rconst,
    float* __restrict__ ws)
{
    const int st = blockIdx.x;        // st = s*64 + t
    const int m  = threadIdx.x;       // 0..63
    const int s  = st >> 6;

    const float4* M4 = (const float4*)(rconst + (size_t)st * (NN * NN));

    __shared__ float4 stage[NN * 16];          // 16 KB; first 32 reused as vbuf
    float* lds = (float*)stage;

    // ---- Phase 1: load 16 KB coalesced, store XOR-swizzled ----
    float4 tmp[16];
    #pragma unroll
    for (int q = 0; q < 16; ++q)
        tmp[q] = M4[q * 64 + m];               // contiguous 1 KB per instr
    #pragma unroll
    for (int q = 0; q < 16; ++q) {
        const int r = 4 * q + (m >> 4);        // row this float4 belongs to
        const int c = m & 15;                  // chunk within the row
        stage[r * 16 + (c ^ (r & 15))] = tmp[q];   // swizzled, conflict-free
    }
    __syncthreads();

    // ---- Phase 2: row m -> registers (constant indices => SROA-safe) ----
    float4 row[16];
    {
        const float4* src = stage + m * 16;
        const int swz = m & 15;
        #pragma unroll
        for (int q = 0; q < 16; ++q)
            row[q] = src[q ^ swz];             // 8 touches/bank, conflict-free
    }

    // ---- Phase 3: power iteration; vbuf aliases dead staging memory ----
    // (single wave: LDS ops are in program order; stage[] reads above are
    //  complete before these writes retire for any lane)
    lds[m] = 1.0f / NN;                        // vbuf slot 0 = lds[0..63]
    __syncthreads();

    int cur = 0;
    #pragma unroll 1
    for (int it = 0; it < NITER; ++it) {
        const float4* v4 = (const float4*)(lds + (cur ? NN : 0));
        float a0 = 0.f, a1 = 0.f, a2 = 0.f, a3 = 0.f;
        #pragma unroll
        for (int q = 0; q < 16; ++q) {
            float4 v = v4[q];                  // uniform address => broadcast
            a0 += row[q].x * v.x;
            a1 += row[q].y * v.y;
            a2 += row[q].z * v.z;
            a3 += row[q].w * v.w;
        }
        const float acc = (a0 + a1) + (a2 + a3);
        cur ^= 1;
        lds[(cur ? NN : 0) + m] = acc;         // sum(v) preserved, no renorm
        __syncthreads();
    }

    // ---- Epilogue: coef = x*wt*M[s][s] / v[s] (uniform scalar loads) ----
    const float Mss  = rconst[(size_t)st * (NN * NN) + s * NN + s];
    const float* vb  = lds + (cur ? NN : 0);
    const float coef = x[st] * wt[st] * Mss / vb[s];
    ws[(size_t)st * NN + m] = coef * vb[m];    // coalesced 256 B store
}

// Stage 1: 16 blocks; block b reduces sts [256b, 256b+256), fully coalesced.
__global__ __launch_bounds__(256) void reduce1_kernel(
    const float* __restrict__ ws, float* __restrict__ part)
{
    const int b = blockIdx.x;
    const int t = threadIdx.x;
    const int n = t & 63;
    const int g = t >> 6;
    float acc = 0.0f;
    #pragma unroll
    for (int k = 0; k < 64; ++k) {
        const int st = (b << 8) + (k << 2) + g;
        acc += ws[(size_t)st * NN + n];
    }
    __shared__ float p[4][NN];
    p[g][n] = acc;
    __syncthreads();
    if (t < NN) part[b * NN + t] = p[0][t] + p[1][t] + p[2][t] + p[3][t];
}

__global__ __launch_bounds__(64) void reduce2_kernel(
    const float* __restrict__ part, float* __restrict__ out)
{
    const int n = threadIdx.x;
    float acc = 0.0f;
    #pragma unroll
    for (int b = 0; b < 16; ++b) acc += part[b * NN + n];
    out[n] = acc;
}

extern "C" void kernel_launch(void* const* d_in, const int* in_sizes, int n_in,
                              void* d_out, int out_size, void* d_ws, size_t ws_size,
                              hipStream_t stream) {
    const float* x      = (const float*)d_in[0];   // (64,64)
    const float* wt     = (const float*)d_in[1];   // (64,64)
    // d_in[2]=weights_r, d_in[3]=r_zeros unused: weights_r * 0 == 0
    const float* rconst = (const float*)d_in[4];   // (64,64,64,64)
    float* out  = (float*)d_out;                   // (64,)
    float* ws   = (float*)d_ws;                    // 4096*64 floats = 1 MB
    float* part = ws + 4096 * NN;                  // 16*64 floats

    perron_kernel<<<dim3(NN * NN), dim3(NN), 0, stream>>>(x, wt, rconst, ws);
    reduce1_kernel<<<dim3(16), dim3(256), 0, stream>>>(ws, part);
    reduce2_kernel<<<dim3(1), dim3(NN), 0, stream>>>(part, out);
}